// Round 1
// 320.802 us; speedup vs baseline: 1.0031x; 1.0031x over previous
//
#include <hip/hip_runtime.h>

// RandCropResize v4: crop-span staging.
// B=64, C=3, H=W=512, fp32. One block per (b, oy): stages the 6 bilinear
// source rows (2 y-taps x 3 channels) into LDS -- but ONLY the x-crop span
// [X1 & ~3, X1+nx], not the full 512-float row (avg crop ~60% of the row,
// so HBM fetch drops ~40%). x-coords computed once, shared across channels;
// x-gathers read s[ix] and s[ix+1] unconditionally (-> ds_read2_b32); the
// ix0==nx-1 clamp case has wx==0 exactly, and the one-past LDS slot is
// pre-zeroed so the dead read is finite and we never load image column 512
// (which would read OOB on the last row of the tensor).

#define BB 64
#define CC 3
#define HH 512
#define WW 512
#define NB (BB * HH)          // 32768 blocks
#define PITCH 516             // floats per LDS row: <=516 used; 516*4 % 16 == 0

__global__ __launch_bounds__(256) void rand_crop_resize_kernel(
    const float* __restrict__ img,
    const int* __restrict__ y1a, const int* __restrict__ y2a,
    const int* __restrict__ x1a, const int* __restrict__ x2a,
    float* __restrict__ out)
{
    __shared__ float s[6 * PITCH];   // rows: [c*2 + tap], crop-span only

    // XCD swizzle: give XCD k a contiguous slice of 8 batches.
    const int r  = (blockIdx.x & 7) * (NB / 8) + (blockIdx.x >> 3);
    const int oy = r & (HH - 1);
    const int b  = r >> 9;

    const int Y1 = y1a[b], Y2 = y2a[b], X1 = x1a[b], X2 = x2a[b];

    // ---- y coords (uniform) ----
    const int ny_i = Y2 - Y1;
    float sy = ((float)oy + 0.5f) * (float)ny_i * (1.0f / 512.0f) - 0.5f;
    sy = fminf(fmaxf(sy, 0.0f), (float)ny_i - 1.0f);
    int iy0 = (int)sy;                       // sy >= 0, trunc == floor
    const int iy1 = min(iy0 + 1, ny_i - 1) + Y1;
    const float wy = sy - (float)iy0;
    iy0 += Y1;

    const int t = threadIdx.x;

    // ---- crop-span chunk range (uniform) ----
    const int nx_i = X2 - X1;
    const int c0   = X1 >> 2;                          // first float4 chunk
    const int c1   = min((X1 + nx_i) >> 2, (WW >> 2) - 1);  // last chunk, <=127
    const int nch  = c1 - c0 + 1;                      // chunks per row, <=128
    const int xoff = X1 - (c0 << 2);                   // = X1 & 3
    const int zi   = xoff + nx_i;                      // one-past slot, <=515

    // zero the dead slot of each LDS row (read only when wx == 0; also stays
    // zero when X1+nx == 512, where loading it from global would be OOB)
    if (t < 6) s[t * PITCH + zi] = 0.0f;

    // ---- stage 6 crop spans: thread-half g stages rows 3g..3g+2 ----
    const size_t base = (size_t)b * (size_t)(CC * HH * WW);
    const int g  = t >> 7;                   // 0 or 1 (waves 0-1 / 2-3)
    const int tt = t & 127;                  // chunk lane within the row
    if (tt < nch) {
        #pragma unroll
        for (int k = 0; k < 3; ++k) {
            const int rw = g * 3 + k;        // 0..5
            const int c  = rw >> 1;
            const int iy = (rw & 1) ? iy1 : iy0;
            const float4 v = ((const float4*)(img + base
                                 + (size_t)(c * HH + iy) * (size_t)WW))[c0 + tt];
            ((float4*)(s + rw * PITCH))[tt] = v;
        }
    }
    __syncthreads();

    // ---- x bilinear: 2 px/thread, coords shared across 3 channels ----
    const float nx    = (float)nx_i;
    const float nxm1f = nx - 1.0f;

    float2 res[3];
    #pragma unroll
    for (int k = 0; k < 2; ++k) {
        const int ox = 2 * t + k;
        float sx = ((float)ox + 0.5f) * nx * (1.0f / 512.0f) - 0.5f;
        sx = fminf(fmaxf(sx, 0.0f), nxm1f);
        const int   ix0 = (int)sx;           // sx >= 0, trunc == floor
        const float wx  = sx - (float)ix0;
        const int   ix  = xoff + ix0;        // local LDS index; ix+1 <= zi

        #pragma unroll
        for (int c = 0; c < 3; ++c) {
            const float* s0 = s + (2 * c) * PITCH;
            const float* s1 = s0 + PITCH;
            const float v00 = s0[ix];
            const float v01 = s0[ix + 1];    // fuses into ds_read2_b32
            const float v10 = s1[ix];
            const float v11 = s1[ix + 1];
            const float r0 = v00 + (v10 - v00) * wy;
            const float r1 = v01 + (v11 - v01) * wy;
            const float v  = r0 + (r1 - r0) * wx;
            if (k == 0) res[c].x = v; else res[c].y = v;
        }
    }

    #pragma unroll
    for (int c = 0; c < 3; ++c) {
        float2* orow = (float2*)(out
            + ((size_t)(b * CC + c) * (size_t)HH + (size_t)oy) * (size_t)WW);
        orow[t] = res[c];
    }
}

extern "C" void kernel_launch(void* const* d_in, const int* in_sizes, int n_in,
                              void* d_out, int out_size, void* d_ws, size_t ws_size,
                              hipStream_t stream) {
    const float* img = (const float*)d_in[0];
    const int*   y1  = (const int*)d_in[1];
    const int*   y2  = (const int*)d_in[2];
    const int*   x1  = (const int*)d_in[3];
    const int*   x2  = (const int*)d_in[4];
    float*       out = (float*)d_out;

    dim3 grid(NB);      // 32768 blocks, one per (b, oy)
    dim3 block(256);
    hipLaunchKernelGGL(rand_crop_resize_kernel, grid, block, 0, stream,
                       img, y1, y2, x1, x2, out);
}